// Round 3
// baseline (410.736 us; speedup 1.0000x reference)
//
#include <hip/hip_runtime.h>
#include <hip/hip_bf16.h>
#include <cstdint>
#include <cstddef>

#define S_LEN 2048
#define BATCHN 2
#define DMODEL 1024
#define NHEADS 16
#define DHEAD 64
#define DFF 4096
#define NTOK (S_LEN*BATCHN)   // 4096 tokens

typedef __bf16 bf16x8 __attribute__((ext_vector_type(8)));
typedef __bf16 bf16x4 __attribute__((ext_vector_type(4)));
typedef float f32x4 __attribute__((ext_vector_type(4)));
typedef __hip_bfloat16 bf16s;

// Q pre-scale: 1/sqrt(64) * log2(e)  (softmax runs in exp2 domain)
#define QSCALE 0.18033688011112042592f

__device__ static inline void gload_lds16(const void* g, void* l) {
  __builtin_amdgcn_global_load_lds((const __attribute__((address_space(1))) void*)g,
                                   (__attribute__((address_space(3))) void*)l,
                                   16, 0, 0);
}

// ---------------- pack kernels ----------------

// four 1024x1024 f32 -> bf16 transposes in one launch (z selects matrix)
__global__ __launch_bounds__(256) void transpose_convert4(const float* __restrict__ s0,
                                                          const float* __restrict__ s1,
                                                          const float* __restrict__ s2,
                                                          const float* __restrict__ s3,
                                                          bf16s* __restrict__ dst) {
  __shared__ float tile[32][33];
  const float* in = (blockIdx.z == 0) ? s0 : (blockIdx.z == 1) ? s1 : (blockIdx.z == 2) ? s2 : s3;
  bf16s* out = dst + (size_t)blockIdx.z * DMODEL * DMODEL;
  const int tx = threadIdx.x & 31;
  const int ty = threadIdx.x >> 5;
  const int bx = blockIdx.x * 32;
  const int by = blockIdx.y * 32;
#pragma unroll
  for (int i = 0; i < 32; i += 8)
    tile[ty + i][tx] = in[(size_t)(by + ty + i) * DMODEL + bx + tx];
  __syncthreads();
#pragma unroll
  for (int i = 0; i < 32; i += 8)
    out[(size_t)(bx + ty + i) * DMODEL + by + tx] = __float2bfloat16(tile[tx][ty + i]);
}

__global__ __launch_bounds__(256) void transpose_convert(const float* __restrict__ in,
                                                         bf16s* __restrict__ out,
                                                         int K, int N) {
  __shared__ float tile[32][33];
  const int tx = threadIdx.x & 31;
  const int ty = threadIdx.x >> 5;
  const int bx = blockIdx.x * 32;
  const int by = blockIdx.y * 32;
#pragma unroll
  for (int i = 0; i < 32; i += 8)
    tile[ty + i][tx] = in[(size_t)(by + ty + i) * N + bx + tx];
  __syncthreads();
#pragma unroll
  for (int i = 0; i < 32; i += 8)
    out[(size_t)(bx + ty + i) * K + by + tx] = __float2bfloat16(tile[tx][ty + i]);
}

__global__ __launch_bounds__(256) void cvt_bf16_kernel(const float* __restrict__ in,
                                                       bf16s* __restrict__ out, int n4) {
  int i = blockIdx.x * 256 + threadIdx.x;
  if (i < n4) {
    float4 v = ((const float4*)in)[i];
    union { bf16s h[4]; uint2 u; } pk;
    pk.h[0] = __float2bfloat16(v.x); pk.h[1] = __float2bfloat16(v.y);
    pk.h[2] = __float2bfloat16(v.z); pk.h[3] = __float2bfloat16(v.w);
    ((uint2*)out)[i] = pk.u;
  }
}

__global__ __launch_bounds__(256) void bias_concat_kernel(const float* __restrict__ bq,
                                                          const float* __restrict__ bk,
                                                          const float* __restrict__ bv,
                                                          float* __restrict__ bqkv) {
  int i = blockIdx.x * 256 + threadIdx.x;
  if (i < 3 * DMODEL) {
    float v = (i < DMODEL) ? bq[i] : (i < 2 * DMODEL ? bk[i - DMODEL] : bv[i - 2 * DMODEL]);
    bqkv[i] = v;
  }
}

// ---------------- GEMM (m97 structure: 128x128 tile, BK=32, dbuf 32KB) ----------------
template<int EPI>
__global__ __launch_bounds__(256, 3)
void gemm_kernel(const bf16s* __restrict__ A, const bf16s* __restrict__ Bt,
                 int M, int N, int K,
                 const float* __restrict__ bias,
                 const float* __restrict__ residF,
                 const bf16s* __restrict__ residB,
                 float* __restrict__ outF, bf16s* __restrict__ outB,
                 bf16s* __restrict__ Qb, bf16s* __restrict__ Kb, bf16s* __restrict__ Vtb)
{
  __shared__ bf16s smem[2][8192];   // per buf: A 8KB | B 8KB
  const int tid = threadIdx.x;
  const int l = tid & 63;
  const int w = tid >> 6;
  const int m0 = blockIdx.y * 128;
  const int n0 = blockIdx.x * 128;
  const int lr = l & 15, lg = l >> 4;

  f32x4 acc[4][4] = {};

  auto stageAB = [&](int buf, int kt) {
    char* base = (char*)&smem[buf][0];
#pragma unroll
    for (int i = 0; i < 2; ++i) {
      int c = w * 2 + i;                    // 8 chunks of 1KB per region
      int off = c * 1024 + l * 16;
      int row = off >> 6;                   // 64B rows (32 bf16)
      int kb = (off & 63) ^ ((row & 3) << 4);
      gload_lds16((const char*)A + ((size_t)(m0 + row) * K + kt) * 2 + kb, base + off);
      gload_lds16((const char*)Bt + ((size_t)(n0 + row) * K + kt) * 2 + kb, base + 8192 + off);
    }
  };

  const int wm = (w >> 1) * 64, wn = (w & 1) * 64;

  auto compute = [&](int buf) {
    const char* base = (const char*)&smem[buf][0];
    bf16x8 af[4], bfr[4];
#pragma unroll
    for (int mi = 0; mi < 4; ++mi) {
      int row = wm + mi * 16 + lr;
      af[mi] = *(const bf16x8*)(base + row * 64 + ((lg * 16) ^ ((row & 3) << 4)));
    }
#pragma unroll
    for (int ni = 0; ni < 4; ++ni) {
      int row = wn + ni * 16 + lr;
      bfr[ni] = *(const bf16x8*)(base + 8192 + row * 64 + ((lg * 16) ^ ((row & 3) << 4)));
    }
#pragma unroll
    for (int mi = 0; mi < 4; ++mi)
#pragma unroll
      for (int ni = 0; ni < 4; ++ni)
        acc[mi][ni] = __builtin_amdgcn_mfma_f32_16x16x32_bf16(af[mi], bfr[ni], acc[mi][ni], 0, 0, 0);
  };

  const int nt = K / 32;
  stageAB(0, 0);
  __syncthreads();
  int cur = 0;
  for (int t = 0; t < nt - 1; ++t) {
    stageAB(cur ^ 1, (t + 1) * 32);
    compute(cur);
    __syncthreads();
    cur ^= 1;
  }
  compute(cur);

  // epilogue
#pragma unroll
  for (int mi = 0; mi < 4; ++mi) {
#pragma unroll
    for (int ni = 0; ni < 4; ++ni) {
#pragma unroll
      for (int r = 0; r < 4; ++r) {
        int row = m0 + wm + mi * 16 + lg * 4 + r;
        int col = n0 + wn + ni * 16 + lr;
        float v = acc[mi][ni][r] + bias[col];
        if (EPI == 0) {
          int which = col >> 10;
          int h = (col & 1023) >> 6;
          int d = col & 63;
          int b = row & 1;
          int s = row >> 1;
          if (which == 0)
            Qb[(((size_t)(b * NHEADS + h)) * S_LEN + s) * DHEAD + d] = __float2bfloat16(v * QSCALE);
          else if (which == 1)
            Kb[(((size_t)(b * NHEADS + h)) * S_LEN + s) * DHEAD + d] = __float2bfloat16(v);
          else
            Vtb[(((size_t)(b * NHEADS + h)) * DHEAD + d) * S_LEN + s] = __float2bfloat16(v);
        } else if (EPI == 1) {
          outF[(size_t)row * N + col] = v + residF[(size_t)row * N + col];
        } else if (EPI == 2) {
          float gv = 0.5f * v * (1.0f + erff(v * 0.70710678118654752f));
          outB[(size_t)row * N + col] = __float2bfloat16(gv);
        } else {
          outF[(size_t)row * N + col] = v + __bfloat162float(residB[(size_t)row * N + col]);
        }
      }
    }
  }
}

// ---------------- flash attention (swapped-QK^T, 16 q-rows/wave) ----------------
// grid: 1024 blocks (XCD-swizzled), 256 threads = 4 waves x 16 q-rows -> 64 q/block.
// KV tile = 64, double-buffered in LDS via global_load_lds + XOR swizzle.
// LDS: [buf0: K 8K | V 8K][buf1: K 8K | V 8K][P: 4 waves x 16 x 144B] = 41984B -> 3 blk/CU
__global__ __launch_bounds__(256, 3)
void attn_kernel(const bf16s* __restrict__ Qb, const bf16s* __restrict__ Kb,
                 const bf16s* __restrict__ Vtb, bf16s* __restrict__ ctx)
{
  __shared__ __align__(1024) char lds[41984];
  const int tid = threadIdx.x;
  const int l = tid & 63, w = tid >> 6;
  const int lr = l & 15, lg = l >> 4;

  // XCD-chunked bijective swizzle: 1024 = 8 * 128
  int lin = blockIdx.x;
  int wg = (lin & 7) * 128 + (lin >> 3);
  int qb = wg & 31;          // 32 q-blocks of 64
  int hb = wg >> 5;          // 0..31
  int h = hb & 15, b = hb >> 4;

  const char* Qg = (const char*)(Qb + ((size_t)(b * NHEADS + h)) * S_LEN * DHEAD);
  const char* Kg = (const char*)(Kb + ((size_t)(b * NHEADS + h)) * S_LEN * DHEAD);
  const char* Vg = (const char*)(Vtb + ((size_t)(b * NHEADS + h)) * DHEAD * S_LEN);

  const int swz = (lr & 7) << 4;
  const int aK0 = lr * 128 + ((lg * 16) ^ swz);          // frag addr, kk=0
  const int aK1 = lr * 128 + ((64 + lg * 16) ^ swz);     // frag addr, kk=1
  const int klane = (l >> 3) * 128  + (((l & 7) * 16) ^ ((l & 56) << 1));  // K stage src
  const int vlane = (l >> 3) * 4096 + (((l & 7) * 16) ^ ((l & 56) << 1));  // V stage src
  const int l16 = l * 16;
  char* Pw = lds + 32768 + w * 2304;       // 16 rows x 144B
  const int pwA = lr * 144 + lg * 8;
  const int prA = lr * 144 + lg * 16;

  const int q0 = qb * 64 + w * 16;
  bf16x8 aq[2];
#pragma unroll
  for (int kk = 0; kk < 2; ++kk)
    aq[kk] = *(const bf16x8*)(Qg + (size_t)(q0 + lr) * 128 + kk * 64 + lg * 16);

  f32x4 o0[4] = {};
  float m0 = -1e30f;
  float ls0 = 0.f;

  const int NT = S_LEN / 64;

  auto stage = [&](char* dK, int tile) {
    const char* kbg = Kg + (size_t)tile * 8192;
    const char* vbg = Vg + (size_t)tile * 128;
    char* dV = dK + 8192;
#pragma unroll
    for (int i = 0; i < 2; ++i) {
      int c = w * 2 + i;
      gload_lds16(kbg + c * 1024 + klane, dK + c * 1024 + l16);
      gload_lds16(vbg + (size_t)c * 32768 + vlane, dV + c * 1024 + l16);
    }
  };

  stage(lds, 0);
  asm volatile("s_waitcnt vmcnt(0)" ::: "memory");
  __builtin_amdgcn_s_barrier();

#define ATTN_ITER(BUF, t)                                                        \
  {                                                                              \
    int nxt = ((t) + 1 < NT) ? (t) + 1 : NT - 1;                                 \
    stage(lds + ((BUF) ^ 1) * 16384, nxt);                                       \
    const char* bK = lds + (BUF) * 16384;                                        \
    const char* bV = bK + 8192;                                                  \
    f32x4 st0[4];                                                                \
    _Pragma("unroll")                                                            \
    for (int ni = 0; ni < 4; ++ni) {                                             \
      bf16x8 k0 = *(const bf16x8*)(bK + ni * 2048 + aK0);                        \
      bf16x8 k1 = *(const bf16x8*)(bK + ni * 2048 + aK1);                        \
      f32x4 z = {};                                                              \
      st0[ni] = __builtin_amdgcn_mfma_f32_16x16x32_bf16(k0, aq[0], z, 0, 0, 0);  \
      st0[ni] = __builtin_amdgcn_mfma_f32_16x16x32_bf16(k1, aq[1], st0[ni], 0, 0, 0);\
    }                                                                            \
    f32x4 vm0 = st0[0];                                                          \
    _Pragma("unroll")                                                            \
    for (int ni = 1; ni < 4; ++ni) {                                             \
      _Pragma("unroll")                                                          \
      for (int r = 0; r < 4; ++r) vm0[r] = fmaxf(vm0[r], st0[ni][r]);            \
    }                                                                            \
    float mx0 = fmaxf(fmaxf(vm0[0], vm0[1]), fmaxf(vm0[2], vm0[3]));             \
    mx0 = fmaxf(mx0, __shfl_xor(mx0, 16)); mx0 = fmaxf(mx0, __shfl_xor(mx0, 32));\
    if (!__all(mx0 <= m0 + 8.f)) {                                               \
      float nm0 = fmaxf(m0, mx0);                                                \
      float al0 = exp2f(m0 - nm0);                                               \
      m0 = nm0; ls0 *= al0;                                                      \
      _Pragma("unroll")                                                          \
      for (int r = 0; r < 4; ++r) {                                              \
        float s0r = __shfl(al0, lg * 4 + r);                                     \
        _Pragma("unroll")                                                        \
        for (int di = 0; di < 4; ++di) o0[di][r] *= s0r;                         \
      }                                                                          \
    }                                                                            \
    f32x4 ac0 = {};                                                              \
    _Pragma("unroll")                                                            \
    for (int ni = 0; ni < 4; ++ni) {                                             \
      _Pragma("unroll")                                                          \
      for (int r = 0; r < 4; ++r) st0[ni][r] = exp2f(st0[ni][r] - m0);           \
      ac0 += st0[ni];                                                            \
    }                                                                            \
    ls0 += ac0[0] + ac0[1] + ac0[2] + ac0[3];                                    \
    _Pragma("unroll")                                                            \
    for (int ni = 0; ni < 4; ++ni) {                                             \
      bf16x4 p0;                                                                 \
      _Pragma("unroll")                                                          \
      for (int j = 0; j < 4; ++j) p0[j] = (__bf16)st0[ni][j];                    \
      *(bf16x4*)(Pw + pwA + ni * 32) = p0;                                       \
    }                                                                            \
    _Pragma("unroll")                                                            \
    for (int kk = 0; kk < 2; ++kk) {                                             \
      bf16x8 ap0 = *(const bf16x8*)(Pw + prA + kk * 64);                         \
      const int av = kk ? aK1 : aK0;                                             \
      _Pragma("unroll")                                                          \
      for (int di = 0; di < 4; ++di) {                                           \
        bf16x8 vv = *(const bf16x8*)(bV + di * 2048 + av);                       \
        o0[di] = __builtin_amdgcn_mfma_f32_16x16x32_bf16(ap0, vv, o0[di], 0, 0, 0);\
      }                                                                          \
    }                                                                            \
    asm volatile("s_waitcnt vmcnt(0)" ::: "memory");                             \
    __builtin_amdgcn_s_barrier();                                                \
  }

  for (int t = 0; t < NT; t += 2) {
    ATTN_ITER(0, t);
    ATTN_ITER(1, t + 1);
  }
#undef ATTN_ITER

  // epilogue: normalize + write ctx[token][D]
  {
    float ls = ls0;
    ls += __shfl_xor(ls, 16);
    ls += __shfl_xor(ls, 32);
    float inv = 1.0f / ls;
#pragma unroll
    for (int r = 0; r < 4; ++r) {
      float invr = __shfl(inv, lg * 4 + r);
      int srow = q0 + lg * 4 + r;
      int tkn = srow * BATCHN + b;
#pragma unroll
      for (int di = 0; di < 4; ++di) {
        int d = h * DHEAD + di * 16 + lr;
        ctx[(size_t)tkn * DMODEL + d] = __float2bfloat16(o0[di][r] * invr);
      }
    }
  }
}

// ---------------- layernorm ----------------
template<int OUTBF>
__global__ __launch_bounds__(256)
void ln_kernel(const float* __restrict__ in, const float* __restrict__ g,
               const float* __restrict__ be, float* __restrict__ outF,
               bf16s* __restrict__ outB)
{
  const int row = blockIdx.x;
  const int tid = threadIdx.x;
  const float* x = in + (size_t)row * DMODEL;
  float4 v = ((const float4*)x)[tid];
  float s = v.x + v.y + v.z + v.w;
  float s2 = v.x * v.x + v.y * v.y + v.z * v.z + v.w * v.w;
#pragma unroll
  for (int m = 1; m < 64; m <<= 1) { s += __shfl_xor(s, m); s2 += __shfl_xor(s2, m); }
  __shared__ float sm[8];
  const int wv = tid >> 6, l = tid & 63;
  if (l == 0) { sm[wv] = s; sm[4 + wv] = s2; }
  __syncthreads();
  s = sm[0] + sm[1] + sm[2] + sm[3];
  s2 = sm[4] + sm[5] + sm[6] + sm[7];
  float mean = s * (1.0f / DMODEL);
  float var = s2 * (1.0f / DMODEL) - mean * mean;
  float rstd = rsqrtf(var + 1e-5f);
  float4 gv = ((const float4*)g)[tid];
  float4 bv = ((const float4*)be)[tid];
  float o0 = (v.x - mean) * rstd * gv.x + bv.x;
  float o1 = (v.y - mean) * rstd * gv.y + bv.y;
  float o2 = (v.z - mean) * rstd * gv.z + bv.z;
  float o3 = (v.w - mean) * rstd * gv.w + bv.w;
  if (OUTBF) {
    union { bf16s h[4]; uint2 u; } pk;
    pk.h[0] = __float2bfloat16(o0); pk.h[1] = __float2bfloat16(o1);
    pk.h[2] = __float2bfloat16(o2); pk.h[3] = __float2bfloat16(o3);
    ((uint2*)(outB + (size_t)row * DMODEL))[tid] = pk.u;
  } else {
    float4 ov = {o0, o1, o2, o3};
    ((float4*)(outF + (size_t)row * DMODEL))[tid] = ov;
  }
}

// ---------------- launch ----------------
extern "C" void kernel_launch(void* const* d_in, const int* in_sizes, int n_in,
                              void* d_out, int out_size, void* d_ws, size_t ws_size,
                              hipStream_t stream) {
  const float* x  = (const float*)d_in[0];
  const float* Wq = (const float*)d_in[1];
  const float* bq = (const float*)d_in[2];
  const float* Wk = (const float*)d_in[3];
  const float* bk = (const float*)d_in[4];
  const float* Wv = (const float*)d_in[5];
  const float* bv = (const float*)d_in[6];
  const float* Wo = (const float*)d_in[7];
  const float* bo = (const float*)d_in[8];
  const float* W1 = (const float*)d_in[9];
  const float* b1 = (const float*)d_in[10];
  const float* W2 = (const float*)d_in[11];
  const float* b2 = (const float*)d_in[12];
  const float* g1 = (const float*)d_in[13];
  const float* be1 = (const float*)d_in[14];
  const float* g2 = (const float*)d_in[15];
  const float* be2 = (const float*)d_in[16];

  char* ws = (char*)d_ws;
  size_t off = 0;
  auto alloc = [&](size_t bytes) -> void* {
    void* p = ws + off;
    off += (bytes + 255) & ~(size_t)255;
    return p;
  };
  bf16s* Wqkv_t = (bf16s*)alloc((size_t)3 * DMODEL * DMODEL * 2);
  bf16s* Wo_t   = (bf16s*)alloc((size_t)DMODEL * DMODEL * 2);
  bf16s* W1_t   = (bf16s*)alloc((size_t)DFF * DMODEL * 2);
  bf16s* W2_t   = (bf16s*)alloc((size_t)DMODEL * DFF * 2);
  float* bqkv   = (float*)alloc((size_t)3 * DMODEL * 4);
  bf16s* Xb     = (bf16s*)alloc((size_t)NTOK * DMODEL * 2);
  bf16s* Qb     = (bf16s*)alloc((size_t)NTOK * DMODEL * 2);
  bf16s* Kb     = (bf16s*)alloc((size_t)NTOK * DMODEL * 2);
  bf16s* Vtb    = (bf16s*)alloc((size_t)NTOK * DMODEL * 2);
  bf16s* ctx    = (bf16s*)alloc((size_t)NTOK * DMODEL * 2);
  float* s1     = (float*)alloc((size_t)NTOK * DMODEL * 4);
  bf16s* y1     = (bf16s*)alloc((size_t)NTOK * DMODEL * 2);
  bf16s* Hb     = (bf16s*)alloc((size_t)NTOK * DFF * 2);
  if (off > ws_size) return;

  // pack (Wq,Wk,Wv -> Wqkv_t; Wo -> Wo_t which is contiguous after Wqkv_t)
  transpose_convert4<<<dim3(32, 32, 4), 256, 0, stream>>>(Wq, Wk, Wv, Wo, Wqkv_t);
  transpose_convert<<<dim3(DFF / 32, DMODEL / 32), 256, 0, stream>>>(W1, W1_t, DMODEL, DFF);
  transpose_convert<<<dim3(DMODEL / 32, DFF / 32), 256, 0, stream>>>(W2, W2_t, DFF, DMODEL);
  bias_concat_kernel<<<12, 256, 0, stream>>>(bq, bk, bv, bqkv);
  cvt_bf16_kernel<<<(NTOK * DMODEL / 4 + 255) / 256, 256, 0, stream>>>(x, Xb, NTOK * DMODEL / 4);

  gemm_kernel<0><<<dim3(3 * DMODEL / 128, NTOK / 128), 256, 0, stream>>>(
      Xb, Wqkv_t, NTOK, 3 * DMODEL, DMODEL, bqkv, nullptr, nullptr, nullptr, nullptr, Qb, Kb, Vtb);

  attn_kernel<<<1024, 256, 0, stream>>>(Qb, Kb, Vtb, ctx);

  gemm_kernel<1><<<dim3(DMODEL / 128, NTOK / 128), 256, 0, stream>>>(
      ctx, Wo_t, NTOK, DMODEL, DMODEL, bo, x, nullptr, s1, nullptr, nullptr, nullptr, nullptr);
  ln_kernel<1><<<NTOK, 256, 0, stream>>>(s1, g1, be1, nullptr, y1);
  gemm_kernel<2><<<dim3(DFF / 128, NTOK / 128), 256, 0, stream>>>(
      y1, W1_t, NTOK, DFF, DMODEL, b1, nullptr, nullptr, nullptr, Hb, nullptr, nullptr, nullptr);
  gemm_kernel<3><<<dim3(DMODEL / 128, NTOK / 128), 256, 0, stream>>>(
      Hb, W2_t, NTOK, DMODEL, DFF, b2, nullptr, y1, s1, nullptr, nullptr, nullptr, nullptr);
  ln_kernel<0><<<NTOK, 256, 0, stream>>>(s1, g2, be2, (float*)d_out, nullptr);
}

// Round 4
// 410.169 us; speedup vs baseline: 1.0014x; 1.0014x over previous
//
#include <hip/hip_runtime.h>
#include <hip/hip_bf16.h>
#include <cstdint>
#include <cstddef>

#define S_LEN 2048
#define BATCHN 2
#define DMODEL 1024
#define NHEADS 16
#define DHEAD 64
#define DFF 4096
#define NTOK (S_LEN*BATCHN)   // 4096 tokens

typedef __bf16 bf16x8 __attribute__((ext_vector_type(8)));
typedef __bf16 bf16x4 __attribute__((ext_vector_type(4)));
typedef float f32x4 __attribute__((ext_vector_type(4)));
typedef __hip_bfloat16 bf16s;

// Q pre-scale: 1/sqrt(64) * log2(e)  (softmax runs in exp2 domain)
#define QSCALE 0.18033688011112042592f

__device__ static inline void gload_lds16(const void* g, void* l) {
  __builtin_amdgcn_global_load_lds((const __attribute__((address_space(1))) void*)g,
                                   (__attribute__((address_space(3))) void*)l,
                                   16, 0, 0);
}

// ---------------- pack kernels ----------------

__global__ __launch_bounds__(256) void transpose_convert4(const float* __restrict__ s0,
                                                          const float* __restrict__ s1,
                                                          const float* __restrict__ s2,
                                                          const float* __restrict__ s3,
                                                          bf16s* __restrict__ dst) {
  __shared__ float tile[32][33];
  const float* in = (blockIdx.z == 0) ? s0 : (blockIdx.z == 1) ? s1 : (blockIdx.z == 2) ? s2 : s3;
  bf16s* out = dst + (size_t)blockIdx.z * DMODEL * DMODEL;
  const int tx = threadIdx.x & 31;
  const int ty = threadIdx.x >> 5;
  const int bx = blockIdx.x * 32;
  const int by = blockIdx.y * 32;
#pragma unroll
  for (int i = 0; i < 32; i += 8)
    tile[ty + i][tx] = in[(size_t)(by + ty + i) * DMODEL + bx + tx];
  __syncthreads();
#pragma unroll
  for (int i = 0; i < 32; i += 8)
    out[(size_t)(bx + ty + i) * DMODEL + by + tx] = __float2bfloat16(tile[tx][ty + i]);
}

__global__ __launch_bounds__(256) void transpose_convert(const float* __restrict__ in,
                                                         bf16s* __restrict__ out,
                                                         int K, int N) {
  __shared__ float tile[32][33];
  const int tx = threadIdx.x & 31;
  const int ty = threadIdx.x >> 5;
  const int bx = blockIdx.x * 32;
  const int by = blockIdx.y * 32;
#pragma unroll
  for (int i = 0; i < 32; i += 8)
    tile[ty + i][tx] = in[(size_t)(by + ty + i) * N + bx + tx];
  __syncthreads();
#pragma unroll
  for (int i = 0; i < 32; i += 8)
    out[(size_t)(bx + ty + i) * K + by + tx] = __float2bfloat16(tile[tx][ty + i]);
}

__global__ __launch_bounds__(256) void cvt_bf16_kernel(const float* __restrict__ in,
                                                       bf16s* __restrict__ out, int n4) {
  int i = blockIdx.x * 256 + threadIdx.x;
  if (i < n4) {
    float4 v = ((const float4*)in)[i];
    union { bf16s h[4]; uint2 u; } pk;
    pk.h[0] = __float2bfloat16(v.x); pk.h[1] = __float2bfloat16(v.y);
    pk.h[2] = __float2bfloat16(v.z); pk.h[3] = __float2bfloat16(v.w);
    ((uint2*)out)[i] = pk.u;
  }
}

__global__ __launch_bounds__(256) void bias_concat_kernel(const float* __restrict__ bq,
                                                          const float* __restrict__ bk,
                                                          const float* __restrict__ bv,
                                                          float* __restrict__ bqkv) {
  int i = blockIdx.x * 256 + threadIdx.x;
  if (i < 3 * DMODEL) {
    float v = (i < DMODEL) ? bq[i] : (i < 2 * DMODEL ? bk[i - DMODEL] : bv[i - 2 * DMODEL]);
    bqkv[i] = v;
  }
}

// epilogue helper (shared by both GEMMs)
template<int EPI>
__device__ static inline void epi_store(int row, int col, int N, float v,
                                        const float* __restrict__ residF,
                                        const bf16s* __restrict__ residB,
                                        float* __restrict__ outF, bf16s* __restrict__ outB,
                                        bf16s* __restrict__ Qb, bf16s* __restrict__ Kb,
                                        bf16s* __restrict__ Vtb) {
  if (EPI == 0) {
    int which = col >> 10;
    int h = (col & 1023) >> 6;
    int d = col & 63;
    int b = row & 1;
    int s = row >> 1;
    if (which == 0)
      Qb[(((size_t)(b * NHEADS + h)) * S_LEN + s) * DHEAD + d] = __float2bfloat16(v * QSCALE);
    else if (which == 1)
      Kb[(((size_t)(b * NHEADS + h)) * S_LEN + s) * DHEAD + d] = __float2bfloat16(v);
    else
      Vtb[(((size_t)(b * NHEADS + h)) * DHEAD + d) * S_LEN + s] = __float2bfloat16(v);
  } else if (EPI == 1) {
    outF[(size_t)row * N + col] = v + residF[(size_t)row * N + col];
  } else if (EPI == 2) {
    float gv = 0.5f * v * (1.0f + erff(v * 0.70710678118654752f));
    outB[(size_t)row * N + col] = __float2bfloat16(gv);
  } else {
    outF[(size_t)row * N + col] = v + __bfloat162float(residB[(size_t)row * N + col]);
  }
}

// ---------------- GEMM 256x256 (8 waves, 3-buffer counted-vmcnt pipeline) ----------------
// BK=32. LDS: 3 buffers x (A 16KB | B 16KB) = 96KB. Stage 2 tiles ahead; vmcnt(4) per tile.
template<int EPI>
__global__ __launch_bounds__(512, 2)
void gemm256_kernel(const bf16s* __restrict__ A, const bf16s* __restrict__ Bt,
                    int M, int N, int K,
                    const float* __restrict__ bias,
                    const float* __restrict__ residF,
                    const bf16s* __restrict__ residB,
                    float* __restrict__ outF, bf16s* __restrict__ outB,
                    bf16s* __restrict__ Qb, bf16s* __restrict__ Kb, bf16s* __restrict__ Vtb)
{
  __shared__ __align__(1024) char smem[3 * 32768];
  const int tid = threadIdx.x;
  const int l = tid & 63, w = tid >> 6;
  const int m0 = blockIdx.y * 256;
  const int n0 = blockIdx.x * 256;
  const int lr = l & 15, lg = l >> 4;
  const int wmB = (w >> 2) * 128, wnB = (w & 3) * 64;

  f32x4 acc[8][4] = {};

  auto stage = [&](int buf, int kt) {
    char* base = smem + buf * 32768;
#pragma unroll
    for (int c = 0; c < 2; ++c) {
      int off = c * 8192 + tid * 16;
      int row = off >> 6;
      int kb = (off & 63) ^ ((row & 3) << 4);
      gload_lds16((const char*)A + ((size_t)(m0 + row) * K + kt * 32) * 2 + kb, base + off);
    }
#pragma unroll
    for (int c = 0; c < 2; ++c) {
      int off = c * 8192 + tid * 16;
      int row = off >> 6;
      int kb = (off & 63) ^ ((row & 3) << 4);
      gload_lds16((const char*)Bt + ((size_t)(n0 + row) * K + kt * 32) * 2 + kb, base + 16384 + off);
    }
  };

  auto compute = [&](int buf) {
    const char* base = smem + buf * 32768;
    bf16x8 bfr[4];
#pragma unroll
    for (int ni = 0; ni < 4; ++ni) {
      int row = wnB + ni * 16 + lr;
      bfr[ni] = *(const bf16x8*)(base + 16384 + row * 64 + ((lg * 16) ^ ((row & 3) << 4)));
    }
#pragma unroll
    for (int mi = 0; mi < 8; ++mi) {
      int row = wmB + mi * 16 + lr;
      bf16x8 af = *(const bf16x8*)(base + row * 64 + ((lg * 16) ^ ((row & 3) << 4)));
#pragma unroll
      for (int ni = 0; ni < 4; ++ni)
        acc[mi][ni] = __builtin_amdgcn_mfma_f32_16x16x32_bf16(af, bfr[ni], acc[mi][ni], 0, 0, 0);
    }
  };

  const int nt = K / 32;
  stage(0, 0);
  stage(1, 1);
  int cur = 0;
  for (int t = 0; t < nt - 1; ++t) {
    asm volatile("s_waitcnt vmcnt(4)" ::: "memory");
    __builtin_amdgcn_s_barrier();
    __builtin_amdgcn_sched_barrier(0);
    if (t + 2 < nt) {
      int sb = cur + 2; if (sb >= 3) sb -= 3;
      stage(sb, t + 2);
    }
    compute(cur);
    if (++cur == 3) cur = 0;
  }
  asm volatile("s_waitcnt vmcnt(0)" ::: "memory");
  __builtin_amdgcn_s_barrier();
  __builtin_amdgcn_sched_barrier(0);
  compute(cur);

#pragma unroll
  for (int mi = 0; mi < 8; ++mi)
#pragma unroll
    for (int ni = 0; ni < 4; ++ni)
#pragma unroll
      for (int r = 0; r < 4; ++r) {
        int row = m0 + wmB + mi * 16 + lg * 4 + r;
        int col = n0 + wnB + ni * 16 + lr;
        epi_store<EPI>(row, col, N, acc[mi][ni][r] + bias[col],
                       residF, residB, outF, outB, Qb, Kb, Vtb);
      }
}

// ---------------- GEMM 128x128 (4 waves, 3-buffer counted-vmcnt pipeline) ----------------
// BK=32. LDS: 3 x (A 8KB | B 8KB) = 48KB -> 3 blocks/CU.
template<int EPI>
__global__ __launch_bounds__(256, 3)
void gemm128_kernel(const bf16s* __restrict__ A, const bf16s* __restrict__ Bt,
                    int M, int N, int K,
                    const float* __restrict__ bias,
                    const float* __restrict__ residF,
                    const bf16s* __restrict__ residB,
                    float* __restrict__ outF, bf16s* __restrict__ outB)
{
  __shared__ __align__(1024) char smem[3 * 16384];
  const int tid = threadIdx.x;
  const int l = tid & 63, w = tid >> 6;
  const int m0 = blockIdx.y * 128;
  const int n0 = blockIdx.x * 128;
  const int lr = l & 15, lg = l >> 4;
  const int wm = (w >> 1) * 64, wn = (w & 1) * 64;

  f32x4 acc[4][4] = {};

  auto stage = [&](int buf, int kt) {
    char* base = smem + buf * 16384;
#pragma unroll
    for (int c = 0; c < 2; ++c) {
      int off = c * 4096 + tid * 16;
      int row = off >> 6;
      int kb = (off & 63) ^ ((row & 3) << 4);
      gload_lds16((const char*)A + ((size_t)(m0 + row) * K + kt * 32) * 2 + kb, base + off);
    }
#pragma unroll
    for (int c = 0; c < 2; ++c) {
      int off = c * 4096 + tid * 16;
      int row = off >> 6;
      int kb = (off & 63) ^ ((row & 3) << 4);
      gload_lds16((const char*)Bt + ((size_t)(n0 + row) * K + kt * 32) * 2 + kb, base + 8192 + off);
    }
  };

  auto compute = [&](int buf) {
    const char* base = smem + buf * 16384;
    bf16x8 af[4], bfr[4];
#pragma unroll
    for (int mi = 0; mi < 4; ++mi) {
      int row = wm + mi * 16 + lr;
      af[mi] = *(const bf16x8*)(base + row * 64 + ((lg * 16) ^ ((row & 3) << 4)));
    }
#pragma unroll
    for (int ni = 0; ni < 4; ++ni) {
      int row = wn + ni * 16 + lr;
      bfr[ni] = *(const bf16x8*)(base + 8192 + row * 64 + ((lg * 16) ^ ((row & 3) << 4)));
    }
#pragma unroll
    for (int mi = 0; mi < 4; ++mi)
#pragma unroll
      for (int ni = 0; ni < 4; ++ni)
        acc[mi][ni] = __builtin_amdgcn_mfma_f32_16x16x32_bf16(af[mi], bfr[ni], acc[mi][ni], 0, 0, 0);
  };

  const int nt = K / 32;
  stage(0, 0);
  stage(1, 1);
  int cur = 0;
  for (int t = 0; t < nt - 1; ++t) {
    asm volatile("s_waitcnt vmcnt(4)" ::: "memory");
    __builtin_amdgcn_s_barrier();
    __builtin_amdgcn_sched_barrier(0);
    if (t + 2 < nt) {
      int sb = cur + 2; if (sb >= 3) sb -= 3;
      stage(sb, t + 2);
    }
    compute(cur);
    if (++cur == 3) cur = 0;
  }
  asm volatile("s_waitcnt vmcnt(0)" ::: "memory");
  __builtin_amdgcn_s_barrier();
  __builtin_amdgcn_sched_barrier(0);
  compute(cur);

#pragma unroll
  for (int mi = 0; mi < 4; ++mi)
#pragma unroll
    for (int ni = 0; ni < 4; ++ni)
#pragma unroll
      for (int r = 0; r < 4; ++r) {
        int row = m0 + wm + mi * 16 + lg * 4 + r;
        int col = n0 + wn + ni * 16 + lr;
        epi_store<EPI>(row, col, N, acc[mi][ni][r] + bias[col],
                       residF, residB, outF, outB, nullptr, nullptr, nullptr);
      }
}

// ---------------- flash attention (round-2 version: 4 waves x 32 q-rows) ----------------
__global__ __launch_bounds__(256, 2)
void attn_kernel(const bf16s* __restrict__ Qb, const bf16s* __restrict__ Kb,
                 const bf16s* __restrict__ Vtb, bf16s* __restrict__ ctx)
{
  __shared__ __align__(1024) char lds[51200];
  const int tid = threadIdx.x;
  const int l = tid & 63, w = tid >> 6;
  const int lr = l & 15, lg = l >> 4;

  // XCD-chunked bijective swizzle: 512 = 8 * 64
  int lin = blockIdx.x;
  int wg = (lin & 7) * 64 + (lin >> 3);
  int qb = wg & 15;
  int hb = wg >> 4;
  int h = hb & 15, b = hb >> 4;

  const char* Qg = (const char*)(Qb + ((size_t)(b * NHEADS + h)) * S_LEN * DHEAD);
  const char* Kg = (const char*)(Kb + ((size_t)(b * NHEADS + h)) * S_LEN * DHEAD);
  const char* Vg = (const char*)(Vtb + ((size_t)(b * NHEADS + h)) * DHEAD * S_LEN);

  const int swz = (lr & 7) << 4;
  const int aK0 = lr * 128 + ((lg * 16) ^ swz);
  const int aK1 = lr * 128 + ((64 + lg * 16) ^ swz);
  const int klane = (l >> 3) * 128  + (((l & 7) * 16) ^ ((l & 56) << 1));
  const int vlane = (l >> 3) * 4096 + (((l & 7) * 16) ^ ((l & 56) << 1));
  const int l16 = l * 16;
  char* Pw = lds + 32768 + w * 4608;
  const int pwA = lr * 144 + lg * 8;
  const int prA = lr * 144 + lg * 16;

  const int q0 = qb * 128 + w * 32;
  bf16x8 aq[2][2];
#pragma unroll
  for (int qi = 0; qi < 2; ++qi)
#pragma unroll
    for (int kk = 0; kk < 2; ++kk)
      aq[qi][kk] = *(const bf16x8*)(Qg + (size_t)(q0 + qi * 16 + lr) * 128 + kk * 64 + lg * 16);

  f32x4 o0[4] = {}, o1[4] = {};
  float m0 = -1e30f, m1 = -1e30f;
  float ls0 = 0.f, ls1 = 0.f;

  const int NT = S_LEN / 64;

  auto stage = [&](char* dK, int tile) {
    const char* kbg = Kg + (size_t)tile * 8192;
    const char* vbg = Vg + (size_t)tile * 128;
    char* dV = dK + 8192;
#pragma unroll
    for (int i = 0; i < 2; ++i) {
      int c = w * 2 + i;
      gload_lds16(kbg + c * 1024 + klane, dK + c * 1024 + l16);
      gload_lds16(vbg + (size_t)c * 32768 + vlane, dV + c * 1024 + l16);
    }
  };

  stage(lds, 0);
  asm volatile("s_waitcnt vmcnt(0)" ::: "memory");
  __builtin_amdgcn_s_barrier();

#define ATTN_ITER(BUF, t)                                                        \
  {                                                                              \
    int nxt = ((t) + 1 < NT) ? (t) + 1 : NT - 1;                                 \
    stage(lds + ((BUF) ^ 1) * 16384, nxt);                                       \
    const char* bK = lds + (BUF) * 16384;                                        \
    const char* bV = bK + 8192;                                                  \
    f32x4 st0[4], st1[4];                                                        \
    _Pragma("unroll")                                                            \
    for (int ni = 0; ni < 4; ++ni) {                                             \
      bf16x8 k0 = *(const bf16x8*)(bK + ni * 2048 + aK0);                        \
      bf16x8 k1 = *(const bf16x8*)(bK + ni * 2048 + aK1);                        \
      f32x4 z = {};                                                              \
      st0[ni] = __builtin_amdgcn_mfma_f32_16x16x32_bf16(k0, aq[0][0], z, 0, 0, 0);\
      st0[ni] = __builtin_amdgcn_mfma_f32_16x16x32_bf16(k1, aq[0][1], st0[ni], 0, 0, 0);\
      st1[ni] = __builtin_amdgcn_mfma_f32_16x16x32_bf16(k0, aq[1][0], z, 0, 0, 0);\
      st1[ni] = __builtin_amdgcn_mfma_f32_16x16x32_bf16(k1, aq[1][1], st1[ni], 0, 0, 0);\
    }                                                                            \
    f32x4 vm0 = st0[0], vm1 = st1[0];                                            \
    _Pragma("unroll")                                                            \
    for (int ni = 1; ni < 4; ++ni) {                                             \
      _Pragma("unroll")                                                          \
      for (int r = 0; r < 4; ++r) {                                              \
        vm0[r] = fmaxf(vm0[r], st0[ni][r]);                                      \
        vm1[r] = fmaxf(vm1[r], st1[ni][r]);                                      \
      }                                                                          \
    }                                                                            \
    float mx0 = fmaxf(fmaxf(vm0[0], vm0[1]), fmaxf(vm0[2], vm0[3]));             \
    float mx1 = fmaxf(fmaxf(vm1[0], vm1[1]), fmaxf(vm1[2], vm1[3]));             \
    mx0 = fmaxf(mx0, __shfl_xor(mx0, 16)); mx0 = fmaxf(mx0, __shfl_xor(mx0, 32));\
    mx1 = fmaxf(mx1, __shfl_xor(mx1, 16)); mx1 = fmaxf(mx1, __shfl_xor(mx1, 32));\
    if (!__all(mx0 <= m0 + 8.f && mx1 <= m1 + 8.f)) {                            \
      float nm0 = fmaxf(m0, mx0), nm1 = fmaxf(m1, mx1);                          \
      float al0 = exp2f(m0 - nm0), al1 = exp2f(m1 - nm1);                        \
      m0 = nm0; m1 = nm1; ls0 *= al0; ls1 *= al1;                                \
      _Pragma("unroll")                                                          \
      for (int r = 0; r < 4; ++r) {                                              \
        float s0r = __shfl(al0, lg * 4 + r);                                     \
        float s1r = __shfl(al1, lg * 4 + r);                                     \
        _Pragma("unroll")                                                        \
        for (int di = 0; di < 4; ++di) { o0[di][r] *= s0r; o1[di][r] *= s1r; }   \
      }                                                                          \
    }                                                                            \
    f32x4 ac0 = {}, ac1 = {};                                                    \
    _Pragma("unroll")                                                            \
    for (int ni = 0; ni < 4; ++ni) {                                             \
      _Pragma("unroll")                                                          \
      for (int r = 0; r < 4; ++r) {                                              \
        st0[ni][r] = exp2f(st0[ni][r] - m0);                                     \
        st1[ni][r] = exp2f(st1[ni][r] - m1);                                     \
      }                                                                          \
      ac0 += st0[ni]; ac1 += st1[ni];                                            \
    }                                                                            \
    ls0 += ac0[0] + ac0[1] + ac0[2] + ac0[3];                                    \
    ls1 += ac1[0] + ac1[1] + ac1[2] + ac1[3];                                    \
    _Pragma("unroll")                                                            \
    for (int ni = 0; ni < 4; ++ni) {                                             \
      bf16x4 p0, p1;                                                             \
      _Pragma("unroll")                                                          \
      for (int j = 0; j < 4; ++j) { p0[j] = (__bf16)st0[ni][j]; p1[j] = (__bf16)st1[ni][j]; }\
      *(bf16x4*)(Pw + pwA + ni * 32) = p0;                                       \
      *(bf16x4*)(Pw + 2304 + pwA + ni * 32) = p1;                                \
    }                                                                            \
    _Pragma("unroll")                                                            \
    for (int kk = 0; kk < 2; ++kk) {                                             \
      bf16x8 ap0 = *(const bf16x8*)(Pw + prA + kk * 64);                         \
      bf16x8 ap1 = *(const bf16x8*)(Pw + 2304 + prA + kk * 64);                  \
      const int av = kk ? aK1 : aK0;                                             \
      _Pragma("unroll")                                                          \
      for (int di = 0; di < 4; ++di) {                                           \
        bf16x8 vv = *(const bf16x8*)(bV + di * 2048 + av);                       \
        o0[di] = __builtin_amdgcn_mfma_f32_16x16x32_bf16(ap0, vv, o0[di], 0, 0, 0);\
        o1[di] = __builtin_amdgcn_mfma_f32_16x16x32_bf16(ap1, vv, o1[di], 0, 0, 0);\
      }                                                                          \
    }                                                                            \
    asm volatile("s_waitcnt vmcnt(0)" ::: "memory");                             \
    __builtin_amdgcn_s_barrier();                                                \
  }

  for (int t = 0; t < NT; t += 2) {
    ATTN_ITER(0, t);
    ATTN_ITER(1, t + 1);
  }
#undef ATTN_ITER

#pragma unroll
  for (int qi = 0; qi < 2; ++qi) {
    float ls = qi ? ls1 : ls0;
    ls += __shfl_xor(ls, 16);
    ls += __shfl_xor(ls, 32);
    float inv = 1.0f / ls;
#pragma unroll
    for (int r = 0; r < 4; ++r) {
      float invr = __shfl(inv, lg * 4 + r);
      int srow = q0 + qi * 16 + lg * 4 + r;
      int tkn = srow * BATCHN + b;
#pragma unroll
      for (int di = 0; di < 4; ++di) {
        int d = h * DHEAD + di * 16 + lr;
        float v = (qi ? o1[di][r] : o0[di][r]) * invr;
        ctx[(size_t)tkn * DMODEL + d] = __float2bfloat16(v);
      }
    }
  }
}

// ---------------- layernorm ----------------
template<int OUTBF>
__global__ __launch_bounds__(256)
void ln_kernel(const float* __restrict__ in, const float* __restrict__ g,
               const float* __restrict__ be, float* __restrict__ outF,
               bf16s* __restrict__ outB)
{
  const int row = blockIdx.x;
  const int tid = threadIdx.x;
  const float* x = in + (size_t)row * DMODEL;
  float4 v = ((const float4*)x)[tid];
  float s = v.x + v.y + v.z + v.w;
  float s2 = v.x * v.x + v.y * v.y + v.z * v.z + v.w * v.w;
#pragma unroll
  for (int m = 1; m < 64; m <<= 1) { s += __shfl_xor(s, m); s2 += __shfl_xor(s2, m); }
  __shared__ float sm[8];
  const int wv = tid >> 6, l = tid & 63;
  if (l == 0) { sm[wv] = s; sm[4 + wv] = s2; }
  __syncthreads();
  s = sm[0] + sm[1] + sm[2] + sm[3];
  s2 = sm[4] + sm[5] + sm[6] + sm[7];
  float mean = s * (1.0f / DMODEL);
  float var = s2 * (1.0f / DMODEL) - mean * mean;
  float rstd = rsqrtf(var + 1e-5f);
  float4 gv = ((const float4*)g)[tid];
  float4 bv = ((const float4*)be)[tid];
  float o0 = (v.x - mean) * rstd * gv.x + bv.x;
  float o1 = (v.y - mean) * rstd * gv.y + bv.y;
  float o2 = (v.z - mean) * rstd * gv.z + bv.z;
  float o3 = (v.w - mean) * rstd * gv.w + bv.w;
  if (OUTBF) {
    union { bf16s h[4]; uint2 u; } pk;
    pk.h[0] = __float2bfloat16(o0); pk.h[1] = __float2bfloat16(o1);
    pk.h[2] = __float2bfloat16(o2); pk.h[3] = __float2bfloat16(o3);
    ((uint2*)(outB + (size_t)row * DMODEL))[tid] = pk.u;
  } else {
    float4 ov = {o0, o1, o2, o3};
    ((float4*)(outF + (size_t)row * DMODEL))[tid] = ov;
  }
}

// ---------------- launch ----------------
extern "C" void kernel_launch(void* const* d_in, const int* in_sizes, int n_in,
                              void* d_out, int out_size, void* d_ws, size_t ws_size,
                              hipStream_t stream) {
  const float* x  = (const float*)d_in[0];
  const float* Wq = (const float*)d_in[1];
  const float* bq = (const float*)d_in[2];
  const float* Wk = (const float*)d_in[3];
  const float* bk = (const float*)d_in[4];
  const float* Wv = (const float*)d_in[5];
  const float* bv = (const float*)d_in[6];
  const float* Wo = (const float*)d_in[7];
  const float* bo = (const float*)d_in[8];
  const float* W1 = (const float*)d_in[9];
  const float* b1 = (const float*)d_in[10];
  const float* W2 = (const float*)d_in[11];
  const float* b2 = (const float*)d_in[12];
  const float* g1 = (const float*)d_in[13];
  const float* be1 = (const float*)d_in[14];
  const float* g2 = (const float*)d_in[15];
  const float* be2 = (const float*)d_in[16];

  char* ws = (char*)d_ws;
  size_t off = 0;
  auto alloc = [&](size_t bytes) -> void* {
    void* p = ws + off;
    off += (bytes + 255) & ~(size_t)255;
    return p;
  };
  bf16s* Wqkv_t = (bf16s*)alloc((size_t)3 * DMODEL * DMODEL * 2);
  bf16s* Wo_t   = (bf16s*)alloc((size_t)DMODEL * DMODEL * 2);
  bf16s* W1_t   = (bf16s*)alloc((size_t)DFF * DMODEL * 2);
  bf16s* W2_t   = (bf16s*)alloc((size_t)DMODEL * DFF * 2);
  float* bqkv   = (float*)alloc((size_t)3 * DMODEL * 4);
  bf16s* Xb     = (bf16s*)alloc((size_t)NTOK * DMODEL * 2);
  bf16s* Qb     = (bf16s*)alloc((size_t)NTOK * DMODEL * 2);
  bf16s* Kb     = (bf16s*)alloc((size_t)NTOK * DMODEL * 2);
  bf16s* Vtb    = (bf16s*)alloc((size_t)NTOK * DMODEL * 2);
  bf16s* ctx    = (bf16s*)alloc((size_t)NTOK * DMODEL * 2);
  float* s1     = (float*)alloc((size_t)NTOK * DMODEL * 4);
  bf16s* y1     = (bf16s*)alloc((size_t)NTOK * DMODEL * 2);
  bf16s* Hb     = (bf16s*)alloc((size_t)NTOK * DFF * 2);
  if (off > ws_size) return;

  transpose_convert4<<<dim3(32, 32, 4), 256, 0, stream>>>(Wq, Wk, Wv, Wo, Wqkv_t);
  transpose_convert<<<dim3(DFF / 32, DMODEL / 32), 256, 0, stream>>>(W1, W1_t, DMODEL, DFF);
  transpose_convert<<<dim3(DMODEL / 32, DFF / 32), 256, 0, stream>>>(W2, W2_t, DFF, DMODEL);
  bias_concat_kernel<<<12, 256, 0, stream>>>(bq, bk, bv, bqkv);
  cvt_bf16_kernel<<<(NTOK * DMODEL / 4 + 255) / 256, 256, 0, stream>>>(x, Xb, NTOK * DMODEL / 4);

  // QKV projection: 256x256 tile pipeline
  gemm256_kernel<0><<<dim3(3 * DMODEL / 256, NTOK / 256), 512, 0, stream>>>(
      Xb, Wqkv_t, NTOK, 3 * DMODEL, DMODEL, bqkv, nullptr, nullptr, nullptr, nullptr, Qb, Kb, Vtb);

  attn_kernel<<<512, 256, 0, stream>>>(Qb, Kb, Vtb, ctx);

  // Wo projection + residual -> s1 (f32): 128x128 pipeline
  gemm128_kernel<1><<<dim3(DMODEL / 128, NTOK / 128), 256, 0, stream>>>(
      ctx, Wo_t, NTOK, DMODEL, DMODEL, bo, x, nullptr, s1, nullptr);
  ln_kernel<1><<<NTOK, 256, 0, stream>>>(s1, g1, be1, nullptr, y1);
  // FF1 + GELU -> Hb (bf16): 256x256 pipeline
  gemm256_kernel<2><<<dim3(DFF / 256, NTOK / 256), 512, 0, stream>>>(
      y1, W1_t, NTOK, DFF, DMODEL, b1, nullptr, nullptr, nullptr, Hb, nullptr, nullptr, nullptr);
  // FF2 + residual(y1) -> s1 (f32): 128x128 pipeline
  gemm128_kernel<3><<<dim3(DMODEL / 128, NTOK / 128), 256, 0, stream>>>(
      Hb, W2_t, NTOK, DMODEL, DFF, b2, nullptr, y1, s1, nullptr);
  ln_kernel<0><<<NTOK, 256, 0, stream>>>(s1, g2, be2, (float*)d_out, nullptr);
}

// Round 5
// 390.450 us; speedup vs baseline: 1.0520x; 1.0505x over previous
//
#include <hip/hip_runtime.h>
#include <hip/hip_bf16.h>
#include <cstdint>
#include <cstddef>

#define S_LEN 2048
#define BATCHN 2
#define DMODEL 1024
#define NHEADS 16
#define DHEAD 64
#define DFF 4096
#define NTOK (S_LEN*BATCHN)   // 4096 tokens

typedef __bf16 bf16x8 __attribute__((ext_vector_type(8)));
typedef __bf16 bf16x4 __attribute__((ext_vector_type(4)));
typedef float f32x4 __attribute__((ext_vector_type(4)));
typedef __hip_bfloat16 bf16s;

// Q pre-scale: 1/sqrt(64) * log2(e)  (softmax runs in exp2 domain)
#define QSCALE 0.18033688011112042592f

__device__ static inline void gload_lds16(const void* g, void* l) {
  __builtin_amdgcn_global_load_lds((const __attribute__((address_space(1))) void*)g,
                                   (__attribute__((address_space(3))) void*)l,
                                   16, 0, 0);
}

// ---------------- pack kernels ----------------

__global__ __launch_bounds__(256) void transpose_convert4(const float* __restrict__ s0,
                                                          const float* __restrict__ s1,
                                                          const float* __restrict__ s2,
                                                          const float* __restrict__ s3,
                                                          bf16s* __restrict__ dst) {
  __shared__ float tile[32][33];
  const float* in = (blockIdx.z == 0) ? s0 : (blockIdx.z == 1) ? s1 : (blockIdx.z == 2) ? s2 : s3;
  bf16s* out = dst + (size_t)blockIdx.z * DMODEL * DMODEL;
  const int tx = threadIdx.x & 31;
  const int ty = threadIdx.x >> 5;
  const int bx = blockIdx.x * 32;
  const int by = blockIdx.y * 32;
#pragma unroll
  for (int i = 0; i < 32; i += 8)
    tile[ty + i][tx] = in[(size_t)(by + ty + i) * DMODEL + bx + tx];
  __syncthreads();
#pragma unroll
  for (int i = 0; i < 32; i += 8)
    out[(size_t)(bx + ty + i) * DMODEL + by + tx] = __float2bfloat16(tile[tx][ty + i]);
}

__global__ __launch_bounds__(256) void transpose_convert(const float* __restrict__ in,
                                                         bf16s* __restrict__ out,
                                                         int K, int N) {
  __shared__ float tile[32][33];
  const int tx = threadIdx.x & 31;
  const int ty = threadIdx.x >> 5;
  const int bx = blockIdx.x * 32;
  const int by = blockIdx.y * 32;
#pragma unroll
  for (int i = 0; i < 32; i += 8)
    tile[ty + i][tx] = in[(size_t)(by + ty + i) * N + bx + tx];
  __syncthreads();
#pragma unroll
  for (int i = 0; i < 32; i += 8)
    out[(size_t)(bx + ty + i) * K + by + tx] = __float2bfloat16(tile[tx][ty + i]);
}

__global__ __launch_bounds__(256) void cvt_bf16_kernel(const float* __restrict__ in,
                                                       bf16s* __restrict__ out, int n4) {
  int i = blockIdx.x * 256 + threadIdx.x;
  if (i < n4) {
    float4 v = ((const float4*)in)[i];
    union { bf16s h[4]; uint2 u; } pk;
    pk.h[0] = __float2bfloat16(v.x); pk.h[1] = __float2bfloat16(v.y);
    pk.h[2] = __float2bfloat16(v.z); pk.h[3] = __float2bfloat16(v.w);
    ((uint2*)out)[i] = pk.u;
  }
}

__global__ __launch_bounds__(256) void bias_concat_kernel(const float* __restrict__ bq,
                                                          const float* __restrict__ bk,
                                                          const float* __restrict__ bv,
                                                          float* __restrict__ bqkv) {
  int i = blockIdx.x * 256 + threadIdx.x;
  if (i < 3 * DMODEL) {
    float v = (i < DMODEL) ? bq[i] : (i < 2 * DMODEL ? bk[i - DMODEL] : bv[i - 2 * DMODEL]);
    bqkv[i] = v;
  }
}

// ---------------- GEMM: exact m97 structure ----------------
// 128x128 tile, BK=32, 4 waves, 2-phase dbuf LDS (2 x 16KB, linear layout),
// global_load_lds w16 staging, plain __syncthreads. grid (N/128, M/128, SPLITK).
// EPI: 0 = QKV scatter (+bqkv, Q*QSCALE)  1 = f32 partial store (no bias)
//      2 = bf16 out (+bias, exact GELU)
template<int EPI>
__global__ __launch_bounds__(256, 3)
void gemm_kernel(const bf16s* __restrict__ A, const bf16s* __restrict__ Bt,
                 int N, int K, int kchunk,
                 const float* __restrict__ bias,
                 float* __restrict__ outF, bf16s* __restrict__ outB,
                 bf16s* __restrict__ Qb, bf16s* __restrict__ Kb, bf16s* __restrict__ Vtb)
{
  __shared__ bf16s smem[2][8192];   // per buf: A 8KB | B 8KB
  const int tid = threadIdx.x;
  const int l = tid & 63, w = tid >> 6;
  const int m0 = blockIdx.y * 128;
  const int n0 = blockIdx.x * 128;
  const int kbeg = blockIdx.z * kchunk;
  const int lr = l & 15, lg = l >> 4;
  const int wm = (w >> 1) * 64, wn = (w & 1) * 64;

  // per-thread staging offsets (linear LDS: [row][64B])
  const int off0 = (w * 2 + 0) * 1024 + l * 16;
  const int off1 = (w * 2 + 1) * 1024 + l * 16;
  const char* a0 = (const char*)(A + (size_t)(m0 + (off0 >> 6)) * K + kbeg) + (off0 & 63);
  const char* a1 = (const char*)(A + (size_t)(m0 + (off1 >> 6)) * K + kbeg) + (off1 & 63);
  const char* b0 = (const char*)(Bt + (size_t)(n0 + (off0 >> 6)) * K + kbeg) + (off0 & 63);
  const char* b1 = (const char*)(Bt + (size_t)(n0 + (off1 >> 6)) * K + kbeg) + (off1 & 63);

  f32x4 acc[4][4] = {};

  auto stage = [&](int buf, int t) {
    char* s = (char*)&smem[buf][0];
    size_t kb = (size_t)t * 64;   // 32 bf16 per K-step
    gload_lds16(a0 + kb, s + off0);
    gload_lds16(a1 + kb, s + off1);
    gload_lds16(b0 + kb, s + 8192 + off0);
    gload_lds16(b1 + kb, s + 8192 + off1);
  };

  const int ao = (wm + lr) * 64 + lg * 16;
  const int bo = 8192 + (wn + lr) * 64 + lg * 16;

  auto compute = [&](int buf) {
    const char* base = (const char*)&smem[buf][0];
    bf16x8 af[4], bfr[4];
#pragma unroll
    for (int mi = 0; mi < 4; ++mi) af[mi] = *(const bf16x8*)(base + ao + mi * 1024);
#pragma unroll
    for (int ni = 0; ni < 4; ++ni) bfr[ni] = *(const bf16x8*)(base + bo + ni * 1024);
#pragma unroll
    for (int mi = 0; mi < 4; ++mi)
#pragma unroll
      for (int ni = 0; ni < 4; ++ni)
        acc[mi][ni] = __builtin_amdgcn_mfma_f32_16x16x32_bf16(af[mi], bfr[ni], acc[mi][ni], 0, 0, 0);
  };

  const int nt = kchunk / 32;
  stage(0, 0);
  __syncthreads();
  int cur = 0;
  for (int t = 0; t < nt - 1; ++t) {
    stage(cur ^ 1, t + 1);
    compute(cur);
    __syncthreads();
    cur ^= 1;
  }
  compute(cur);

  // epilogue
  float* outFz = (EPI == 1) ? outF + (size_t)blockIdx.z * ((size_t)NTOK * DMODEL) : outF;
#pragma unroll
  for (int mi = 0; mi < 4; ++mi) {
#pragma unroll
    for (int ni = 0; ni < 4; ++ni) {
#pragma unroll
      for (int r = 0; r < 4; ++r) {
        int row = m0 + wm + mi * 16 + lg * 4 + r;
        int col = n0 + wn + ni * 16 + lr;
        float v = acc[mi][ni][r];
        if (EPI == 0) {
          v += bias[col];
          int which = col >> 10;
          int h = (col & 1023) >> 6;
          int d = col & 63;
          int b = row & 1;
          int s = row >> 1;
          if (which == 0)
            Qb[(((size_t)(b * NHEADS + h)) * S_LEN + s) * DHEAD + d] = __float2bfloat16(v * QSCALE);
          else if (which == 1)
            Kb[(((size_t)(b * NHEADS + h)) * S_LEN + s) * DHEAD + d] = __float2bfloat16(v);
          else
            Vtb[(((size_t)(b * NHEADS + h)) * DHEAD + d) * S_LEN + s] = __float2bfloat16(v);
        } else if (EPI == 1) {
          outFz[(size_t)row * N + col] = v;
        } else {
          v += bias[col];
          float gv = 0.5f * v * (1.0f + erff(v * 0.70710678118654752f));
          outB[(size_t)row * N + col] = __float2bfloat16(gv);
        }
      }
    }
  }
}

// ---------------- flash attention (round-2 proven: 4 waves x 32 q-rows) ----------------
__global__ __launch_bounds__(256, 2)
void attn_kernel(const bf16s* __restrict__ Qb, const bf16s* __restrict__ Kb,
                 const bf16s* __restrict__ Vtb, bf16s* __restrict__ ctx)
{
  __shared__ __align__(1024) char lds[51200];
  const int tid = threadIdx.x;
  const int l = tid & 63, w = tid >> 6;
  const int lr = l & 15, lg = l >> 4;

  int lin = blockIdx.x;
  int wg = (lin & 7) * 64 + (lin >> 3);
  int qb = wg & 15;
  int hb = wg >> 4;
  int h = hb & 15, b = hb >> 4;

  const char* Qg = (const char*)(Qb + ((size_t)(b * NHEADS + h)) * S_LEN * DHEAD);
  const char* Kg = (const char*)(Kb + ((size_t)(b * NHEADS + h)) * S_LEN * DHEAD);
  const char* Vg = (const char*)(Vtb + ((size_t)(b * NHEADS + h)) * DHEAD * S_LEN);

  const int swz = (lr & 7) << 4;
  const int aK0 = lr * 128 + ((lg * 16) ^ swz);
  const int aK1 = lr * 128 + ((64 + lg * 16) ^ swz);
  const int klane = (l >> 3) * 128  + (((l & 7) * 16) ^ ((l & 56) << 1));
  const int vlane = (l >> 3) * 4096 + (((l & 7) * 16) ^ ((l & 56) << 1));
  const int l16 = l * 16;
  char* Pw = lds + 32768 + w * 4608;
  const int pwA = lr * 144 + lg * 8;
  const int prA = lr * 144 + lg * 16;

  const int q0 = qb * 128 + w * 32;
  bf16x8 aq[2][2];
#pragma unroll
  for (int qi = 0; qi < 2; ++qi)
#pragma unroll
    for (int kk = 0; kk < 2; ++kk)
      aq[qi][kk] = *(const bf16x8*)(Qg + (size_t)(q0 + qi * 16 + lr) * 128 + kk * 64 + lg * 16);

  f32x4 o0[4] = {}, o1[4] = {};
  float m0 = -1e30f, m1 = -1e30f;
  float ls0 = 0.f, ls1 = 0.f;

  const int NT = S_LEN / 64;

  auto stage = [&](char* dK, int tile) {
    const char* kbg = Kg + (size_t)tile * 8192;
    const char* vbg = Vg + (size_t)tile * 128;
    char* dV = dK + 8192;
#pragma unroll
    for (int i = 0; i < 2; ++i) {
      int c = w * 2 + i;
      gload_lds16(kbg + c * 1024 + klane, dK + c * 1024 + l16);
      gload_lds16(vbg + (size_t)c * 32768 + vlane, dV + c * 1024 + l16);
    }
  };

  stage(lds, 0);
  asm volatile("s_waitcnt vmcnt(0)" ::: "memory");
  __builtin_amdgcn_s_barrier();

#define ATTN_ITER(BUF, t)                                                        \
  {                                                                              \
    int nxt = ((t) + 1 < NT) ? (t) + 1 : NT - 1;                                 \
    stage(lds + ((BUF) ^ 1) * 16384, nxt);                                       \
    const char* bK = lds + (BUF) * 16384;                                        \
    const char* bV = bK + 8192;                                                  \
    f32x4 st0[4], st1[4];                                                        \
    _Pragma("unroll")                                                            \
    for (int ni = 0; ni < 4; ++ni) {                                             \
      bf16x8 k0 = *(const bf16x8*)(bK + ni * 2048 + aK0);                        \
      bf16x8 k1 = *(const bf16x8*)(bK + ni * 2048 + aK1);                        \
      f32x4 z = {};                                                              \
      st0[ni] = __builtin_amdgcn_mfma_f32_16x16x32_bf16(k0, aq[0][0], z, 0, 0, 0);\
      st0[ni] = __builtin_amdgcn_mfma_f32_16x16x32_bf16(k1, aq[0][1], st0[ni], 0, 0, 0);\
      st1[ni] = __builtin_amdgcn_mfma_f32_16x16x32_bf16(k0, aq[1][0], z, 0, 0, 0);\
      st1[ni] = __builtin_amdgcn_mfma_f32_16x16x32_bf16(k1, aq[1][1], st1[ni], 0, 0, 0);\
    }                                                                            \
    f32x4 vm0 = st0[0], vm1 = st1[0];                                            \
    _Pragma("unroll")                                                            \
    for (int ni = 1; ni < 4; ++ni) {                                             \
      _Pragma("unroll")                                                          \
      for (int r = 0; r < 4; ++r) {                                              \
        vm0[r] = fmaxf(vm0[r], st0[ni][r]);                                      \
        vm1[r] = fmaxf(vm1[r], st1[ni][r]);                                      \
      }                                                                          \
    }                                                                            \
    float mx0 = fmaxf(fmaxf(vm0[0], vm0[1]), fmaxf(vm0[2], vm0[3]));             \
    float mx1 = fmaxf(fmaxf(vm1[0], vm1[1]), fmaxf(vm1[2], vm1[3]));             \
    mx0 = fmaxf(mx0, __shfl_xor(mx0, 16)); mx0 = fmaxf(mx0, __shfl_xor(mx0, 32));\
    mx1 = fmaxf(mx1, __shfl_xor(mx1, 16)); mx1 = fmaxf(mx1, __shfl_xor(mx1, 32));\
    if (!__all(mx0 <= m0 + 8.f && mx1 <= m1 + 8.f)) {                            \
      float nm0 = fmaxf(m0, mx0), nm1 = fmaxf(m1, mx1);                          \
      float al0 = exp2f(m0 - nm0), al1 = exp2f(m1 - nm1);                        \
      m0 = nm0; m1 = nm1; ls0 *= al0; ls1 *= al1;                                \
      _Pragma("unroll")                                                          \
      for (int r = 0; r < 4; ++r) {                                              \
        float s0r = __shfl(al0, lg * 4 + r);                                     \
        float s1r = __shfl(al1, lg * 4 + r);                                     \
        _Pragma("unroll")                                                        \
        for (int di = 0; di < 4; ++di) { o0[di][r] *= s0r; o1[di][r] *= s1r; }   \
      }                                                                          \
    }                                                                            \
    f32x4 ac0 = {}, ac1 = {};                                                    \
    _Pragma("unroll")                                                            \
    for (int ni = 0; ni < 4; ++ni) {                                             \
      _Pragma("unroll")                                                          \
      for (int r = 0; r < 4; ++r) {                                              \
        st0[ni][r] = exp2f(st0[ni][r] - m0);                                     \
        st1[ni][r] = exp2f(st1[ni][r] - m1);                                     \
      }                                                                          \
      ac0 += st0[ni]; ac1 += st1[ni];                                            \
    }                                                                            \
    ls0 += ac0[0] + ac0[1] + ac0[2] + ac0[3];                                    \
    ls1 += ac1[0] + ac1[1] + ac1[2] + ac1[3];                                    \
    _Pragma("unroll")                                                            \
    for (int ni = 0; ni < 4; ++ni) {                                             \
      bf16x4 p0, p1;                                                             \
      _Pragma("unroll")                                                          \
      for (int j = 0; j < 4; ++j) { p0[j] = (__bf16)st0[ni][j]; p1[j] = (__bf16)st1[ni][j]; }\
      *(bf16x4*)(Pw + pwA + ni * 32) = p0;                                       \
      *(bf16x4*)(Pw + 2304 + pwA + ni * 32) = p1;                                \
    }                                                                            \
    _Pragma("unroll")                                                            \
    for (int kk = 0; kk < 2; ++kk) {                                             \
      bf16x8 ap0 = *(const bf16x8*)(Pw + prA + kk * 64);                         \
      bf16x8 ap1 = *(const bf16x8*)(Pw + 2304 + prA + kk * 64);                  \
      const int av = kk ? aK1 : aK0;                                             \
      _Pragma("unroll")                                                          \
      for (int di = 0; di < 4; ++di) {                                           \
        bf16x8 vv = *(const bf16x8*)(bV + di * 2048 + av);                       \
        o0[di] = __builtin_amdgcn_mfma_f32_16x16x32_bf16(ap0, vv, o0[di], 0, 0, 0);\
        o1[di] = __builtin_amdgcn_mfma_f32_16x16x32_bf16(ap1, vv, o1[di], 0, 0, 0);\
      }                                                                          \
    }                                                                            \
    asm volatile("s_waitcnt vmcnt(0)" ::: "memory");                             \
    __builtin_amdgcn_s_barrier();                                                \
  }

  for (int t = 0; t < NT; t += 2) {
    ATTN_ITER(0, t);
    ATTN_ITER(1, t + 1);
  }
#undef ATTN_ITER

#pragma unroll
  for (int qi = 0; qi < 2; ++qi) {
    float ls = qi ? ls1 : ls0;
    ls += __shfl_xor(ls, 16);
    ls += __shfl_xor(ls, 32);
    float inv = 1.0f / ls;
#pragma unroll
    for (int r = 0; r < 4; ++r) {
      float invr = __shfl(inv, lg * 4 + r);
      int srow = q0 + qi * 16 + lg * 4 + r;
      int tkn = srow * BATCHN + b;
#pragma unroll
      for (int di = 0; di < 4; ++di) {
        int d = h * DHEAD + di * 16 + lr;
        float v = (qi ? o1[di][r] : o0[di][r]) * invr;
        ctx[(size_t)tkn * DMODEL + d] = __float2bfloat16(v);
      }
    }
  }
}

// ---------------- layernorm over (inA + inB + resid + bias) ----------------
// WB=1: write bf16 outB AND f32 outF (y1 + y1f).  WB=0: write f32 outF only.
template<int WB>
__global__ __launch_bounds__(256)
void ln_kernel(const float* __restrict__ inA, const float* __restrict__ inB,
               const float* __restrict__ resid, const float* __restrict__ bias,
               const float* __restrict__ g, const float* __restrict__ be,
               float* __restrict__ outF, bf16s* __restrict__ outB)
{
  const int row = blockIdx.x;
  const int tid = threadIdx.x;
  const size_t base = (size_t)row * DMODEL;
  float4 a = ((const float4*)(inA + base))[tid];
  float4 bq = ((const float4*)(inB + base))[tid];
  float4 rr = ((const float4*)(resid + base))[tid];
  float4 bi = ((const float4*)bias)[tid];
  float4 v;
  v.x = a.x + bq.x + rr.x + bi.x;
  v.y = a.y + bq.y + rr.y + bi.y;
  v.z = a.z + bq.z + rr.z + bi.z;
  v.w = a.w + bq.w + rr.w + bi.w;
  float s = v.x + v.y + v.z + v.w;
  float s2 = v.x * v.x + v.y * v.y + v.z * v.z + v.w * v.w;
#pragma unroll
  for (int m = 1; m < 64; m <<= 1) { s += __shfl_xor(s, m); s2 += __shfl_xor(s2, m); }
  __shared__ float sm[8];
  const int wv = tid >> 6, l = tid & 63;
  if (l == 0) { sm[wv] = s; sm[4 + wv] = s2; }
  __syncthreads();
  s = sm[0] + sm[1] + sm[2] + sm[3];
  s2 = sm[4] + sm[5] + sm[6] + sm[7];
  float mean = s * (1.0f / DMODEL);
  float var = s2 * (1.0f / DMODEL) - mean * mean;
  float rstd = rsqrtf(var + 1e-5f);
  float4 gv = ((const float4*)g)[tid];
  float4 bv = ((const float4*)be)[tid];
  float o0 = (v.x - mean) * rstd * gv.x + bv.x;
  float o1 = (v.y - mean) * rstd * gv.y + bv.y;
  float o2 = (v.z - mean) * rstd * gv.z + bv.z;
  float o3 = (v.w - mean) * rstd * gv.w + bv.w;
  float4 ov = {o0, o1, o2, o3};
  ((float4*)(outF + base))[tid] = ov;
  if (WB) {
    union { bf16s h[4]; uint2 u; } pk;
    pk.h[0] = __float2bfloat16(o0); pk.h[1] = __float2bfloat16(o1);
    pk.h[2] = __float2bfloat16(o2); pk.h[3] = __float2bfloat16(o3);
    ((uint2*)(outB + base))[tid] = pk.u;
  }
}

// ---------------- launch ----------------
extern "C" void kernel_launch(void* const* d_in, const int* in_sizes, int n_in,
                              void* d_out, int out_size, void* d_ws, size_t ws_size,
                              hipStream_t stream) {
  const float* x  = (const float*)d_in[0];
  const float* Wq = (const float*)d_in[1];
  const float* bq = (const float*)d_in[2];
  const float* Wk = (const float*)d_in[3];
  const float* bk = (const float*)d_in[4];
  const float* Wv = (const float*)d_in[5];
  const float* bv = (const float*)d_in[6];
  const float* Wo = (const float*)d_in[7];
  const float* bo = (const float*)d_in[8];
  const float* W1 = (const float*)d_in[9];
  const float* b1 = (const float*)d_in[10];
  const float* W2 = (const float*)d_in[11];
  const float* b2 = (const float*)d_in[12];
  const float* g1 = (const float*)d_in[13];
  const float* be1 = (const float*)d_in[14];
  const float* g2 = (const float*)d_in[15];
  const float* be2 = (const float*)d_in[16];

  char* ws = (char*)d_ws;
  size_t off = 0;
  auto alloc = [&](size_t bytes) -> void* {
    void* p = ws + off;
    off += (bytes + 255) & ~(size_t)255;
    return p;
  };
  bf16s* Wqkv_t = (bf16s*)alloc((size_t)3 * DMODEL * DMODEL * 2);
  bf16s* Wo_t   = (bf16s*)alloc((size_t)DMODEL * DMODEL * 2);
  bf16s* W1_t   = (bf16s*)alloc((size_t)DFF * DMODEL * 2);
  bf16s* W2_t   = (bf16s*)alloc((size_t)DMODEL * DFF * 2);
  float* bqkv   = (float*)alloc((size_t)3 * DMODEL * 4);
  bf16s* Xb     = (bf16s*)alloc((size_t)NTOK * DMODEL * 2);
  bf16s* Qb     = (bf16s*)alloc((size_t)NTOK * DMODEL * 2);   // Hb aliases Qb..ctx (32MB)
  bf16s* Kb     = (bf16s*)alloc((size_t)NTOK * DMODEL * 2);
  bf16s* Vtb    = (bf16s*)alloc((size_t)NTOK * DMODEL * 2);
  bf16s* ctx    = (bf16s*)alloc((size_t)NTOK * DMODEL * 2);
  float* sAB    = (float*)alloc((size_t)2 * NTOK * DMODEL * 4);  // split-K partials (2x16MB)
  bf16s* y1     = (bf16s*)alloc((size_t)NTOK * DMODEL * 2);
  float* y1f    = (float*)alloc((size_t)NTOK * DMODEL * 4);
  bf16s* Hb     = Qb;   // FF1 output aliases dead Q/K/V/ctx region (32MB)
  if (off > ws_size) return;

  float* sA = sAB;
  float* sB = sAB + (size_t)NTOK * DMODEL;

  transpose_convert4<<<dim3(32, 32, 4), 256, 0, stream>>>(Wq, Wk, Wv, Wo, Wqkv_t);
  transpose_convert<<<dim3(DFF / 32, DMODEL / 32), 256, 0, stream>>>(W1, W1_t, DMODEL, DFF);
  transpose_convert<<<dim3(DMODEL / 32, DFF / 32), 256, 0, stream>>>(W2, W2_t, DFF, DMODEL);
  bias_concat_kernel<<<12, 256, 0, stream>>>(bq, bk, bv, bqkv);
  cvt_bf16_kernel<<<(NTOK * DMODEL / 4 + 255) / 256, 256, 0, stream>>>(x, Xb, NTOK * DMODEL / 4);

  // QKV projection: grid 768 (3 blk/CU)
  gemm_kernel<0><<<dim3(24, 32, 1), 256, 0, stream>>>(
      Xb, Wqkv_t, 3 * DMODEL, DMODEL, DMODEL, bqkv, nullptr, nullptr, Qb, Kb, Vtb);

  attn_kernel<<<512, 256, 0, stream>>>(Qb, Kb, Vtb, ctx);

  // Wo projection, split-K x2 -> sA/sB: grid 512 (2 blk/CU)
  gemm_kernel<1><<<dim3(8, 32, 2), 256, 0, stream>>>(
      ctx, Wo_t, DMODEL, DMODEL, DMODEL / 2, nullptr, sAB, nullptr, nullptr, nullptr, nullptr);
  // LN1: (sA + sB + x + bo) -> y1 (bf16) + y1f (f32)
  ln_kernel<1><<<NTOK, 256, 0, stream>>>(sA, sB, x, bo, g1, be1, y1f, y1);
  // FF1 + GELU -> Hb: grid 1024 (3 blk/CU)
  gemm_kernel<2><<<dim3(32, 32, 1), 256, 0, stream>>>(
      y1, W1_t, DFF, DMODEL, DMODEL, b1, nullptr, Hb, nullptr, nullptr, nullptr);
  // FF2, split-K x2 -> sA/sB: grid 512 (2 blk/CU)
  gemm_kernel<1><<<dim3(8, 32, 2), 256, 0, stream>>>(
      Hb, W2_t, DMODEL, DFF, DFF / 2, nullptr, sAB, nullptr, nullptr, nullptr, nullptr);
  // LN2: (sA + sB + y1f + b2) -> d_out (f32)
  ln_kernel<0><<<NTOK, 256, 0, stream>>>(sA, sB, y1f, b2, g2, be2, (float*)d_out, nullptr);
}